// Round 5
// baseline (12634.704 us; speedup 1.0000x reference)
//
#include <hip/hip_runtime.h>
#include <hip/hip_bf16.h>
#include <cstdio>
#include <cstdint>

// MultilayerGRU: B=32, S=512, I=H=O=1024, L=2
// R5: L2-shared staging (plain DMA + acquire-fence/buffer_inv per stage --
//     cheap now that weights live in VGPRs), wave-specialized pipeline
//     (wave0: z + A-prefetch into LDS dbuf; wave1: r, full-K g, h-update,
//     publishes), XCD-aware block swizzle for A/h line dedup.

typedef float f32x4 __attribute__((ext_vector_type(4)));
typedef __bf16 bf16x8 __attribute__((ext_vector_type(8)));
typedef unsigned short u16;

#define AS1 __attribute__((address_space(1)))
#define AS3 __attribute__((address_space(3)))

__device__ inline u16 f2b(float f) {
  __hip_bfloat16 h = __float2bfloat16(f);
  return *reinterpret_cast<u16*>(&h);
}
__device__ inline float b2f(u16 u) {
  __hip_bfloat16 h;
  *reinterpret_cast<u16*>(&h) = u;
  return __bfloat162float(h);
}
__device__ inline bf16x8 ld8(const u16* p) {
  return *reinterpret_cast<const bf16x8*>(p);
}
__device__ inline f32x4 mfma16(bf16x8 a, bf16x8 b, f32x4 c) {
  return __builtin_amdgcn_mfma_f32_16x16x32_bf16(a, b, c, 0, 0, 0);
}

// plain cached global->LDS DMA, 16B/lane (L1+L2; correctness via acquire fence)
__device__ inline void gload_lds16(const void* g, void* l) {
  __builtin_amdgcn_global_load_lds((const AS1 void*)g, (AS3 void*)l, 16, 0, 0);
}

// relaxed agent-scope (LLC-visible) u16 store
__device__ inline void st16(u16* p, u16 v) {
  __hip_atomic_store(p, v, __ATOMIC_RELAXED, __HIP_MEMORY_SCOPE_AGENT);
}

// 64 lanes watch 64 packed epoch flags; exit when all >= target
__device__ inline void poll64(unsigned* f, unsigned target, int lane) {
  unsigned* p = f + lane;
  while (true) {
    unsigned v = __hip_atomic_load(p, __ATOMIC_RELAXED, __HIP_MEMORY_SCOPE_AGENT);
    if (__all((int)(v >= target))) break;
    __builtin_amdgcn_s_sleep(1);
  }
}

// ---------------- elementwise helpers ----------------

__global__ void castk(const float* __restrict__ src, u16* __restrict__ dst, int n) {
  int i = blockIdx.x * 256 + threadIdx.x;
  if (i < n) dst[i] = f2b(src[i]);
}

__global__ void init_h(const float* __restrict__ h0, float* __restrict__ h32_0,
                       float* __restrict__ h32_1, u16* __restrict__ hbf_0,
                       u16* __restrict__ hbf_1) {
  int i = blockIdx.x * 256 + threadIdx.x;
  if (i < 32 * 1024) {
    int b = i >> 10, j = i & 1023;
    float v0 = h0[(b * 2 + 0) * 1024 + j];
    float v1 = h0[(b * 2 + 1) * 1024 + j];
    h32_0[i] = v0; hbf_0[i] = f2b(v0);
    h32_1[i] = v1; hbf_1[i] = f2b(v1);
  }
}

__global__ void final_h(const float* __restrict__ h32_0, const float* __restrict__ h32_1,
                        float* __restrict__ out) {
  int i = blockIdx.x * 256 + threadIdx.x;
  if (i < 32 * 1024) {
    int b = i >> 10, j = i & 1023;
    out[(b * 2 + 0) * 1024 + j] = h32_0[i];
    out[(b * 2 + 1) * 1024 + j] = h32_1[i];
  }
}

// ---------------- big NT GEMM: C[m,n] = sum_k A[m,k]*B[n,k] + bias[n] ----------------
// MODE 0: fp32 store at [m][n].  MODE 2: bf16 store transposed-to-step-major:
// m = b*512 + t  ->  store at [(t*32 + b)][n]  (A buffers for the recurrence).

template <int MODE>
__global__ __launch_bounds__(256, 2) void gemm_nt(const u16* __restrict__ A,
                                                  const u16* __restrict__ B,
                                                  const float* __restrict__ bias,
                                                  void* __restrict__ Cout,
                                                  int M, int N, int K) {
  __shared__ __align__(16) u16 As[128 * 32];
  __shared__ __align__(16) u16 Bs[128 * 32];
  const int tid = threadIdx.x;
  const int lane = tid & 63;
  const int wave = tid >> 6;
  const int tilesN = N >> 7;
  const int bm = blockIdx.x / tilesN, bn = blockIdx.x % tilesN;
  const int wr = (wave >> 1) << 6, wc = (wave & 1) << 6;
  const int la = lane & 15, kg = lane >> 4;
  f32x4 acc[4][4] = {};
  const int srow = tid >> 2, skoff = (tid & 3) << 3;
  const u16* Ap = A + (size_t)(bm * 128 + srow) * K + skoff;
  const u16* Bp = B + (size_t)(bn * 128 + srow) * K + skoff;
  for (int k0 = 0; k0 < K; k0 += 32) {
    gload_lds16(Ap + k0,            As + tid * 8);
    gload_lds16(Ap + (size_t)64 * K + k0, As + 2048 + tid * 8);
    gload_lds16(Bp + k0,            Bs + tid * 8);
    gload_lds16(Bp + (size_t)64 * K + k0, Bs + 2048 + tid * 8);
    __syncthreads();
    bf16x8 af[4], bfr[4];
#pragma unroll
    for (int i = 0; i < 4; ++i) af[i] = ld8(As + (wr + i * 16 + la) * 32 + kg * 8);
#pragma unroll
    for (int j = 0; j < 4; ++j) bfr[j] = ld8(Bs + (wc + j * 16 + la) * 32 + kg * 8);
#pragma unroll
    for (int i = 0; i < 4; ++i)
#pragma unroll
      for (int j = 0; j < 4; ++j)
        acc[i][j] = mfma16(af[i], bfr[j], acc[i][j]);
    __syncthreads();
  }
  const int rbase = bm * 128 + wr + kg * 4;
  const int cbase = bn * 128 + wc + la;
#pragma unroll
  for (int i = 0; i < 4; ++i) {
#pragma unroll
    for (int j = 0; j < 4; ++j) {
      int col = cbase + j * 16;
      float bv = bias[col];
#pragma unroll
      for (int e = 0; e < 4; ++e) {
        int row = rbase + i * 16 + e;
        float v = acc[i][j][e] + bv;
        if (MODE == 0) {
          ((float*)Cout)[(size_t)row * N + col] = v;
        } else {
          int tt = row & 511, bb = row >> 9;
          ((u16*)Cout)[((size_t)(tt * 32 + bb)) * N + col] = f2b(v);
        }
      }
    }
  }
}

// ---------------- persistent GRU layer recurrence, v5 ----------------
// 128 blocks x 128 threads, swizzled so the 4 colT-blocks sharing each 128B
// A/h line land on one XCD (round-robin blockIdx%8 assumption; perf-only).
// wave0: z gate + A(t+1) LDS prefetch. wave1: r gate, full-K g, h update,
// both flag publishes (clean vmcnt at publish). Staging h/rh: plain cached
// DMA shared via XCD L2; correctness from poll + acquire-fence (buffer_inv).

__global__ __launch_bounds__(128, 1) void gru_layer5(
    const u16* __restrict__ Wz, const u16* __restrict__ Wr, const u16* __restrict__ Wg,
    const u16* __restrict__ Az, const u16* __restrict__ Ar, const u16* __restrict__ Ag,
    u16* __restrict__ hist, float* __restrict__ h32g, u16* __restrict__ hbf,
    u16* __restrict__ rhbf, unsigned* __restrict__ flags, int S) {
  __shared__ __align__(16) u16 LDSh[16 * 1024];   // 32 KB staged h / rh rows
  __shared__ __align__(16) u16 Abuf[2][1024];     // A dbuf: [par][z|r|g|pad] 16x16 tiles
  __shared__ float zloc[256];
  __shared__ float h32loc[256];
  const int tid = threadIdx.x, wave = tid >> 6, lane = tid & 63;
  const int la = lane & 15, kg = lane >> 4;
  const int sw = la & 7;
  // swizzle: blocks sharing a 64-col line group (lg) get equal blockIdx%8
  const int low3 = blockIdx.x & 7, vv = blockIdx.x >> 3;
  const int bbit = vv & 1, cpos = (vv >> 1) & 3, rt = vv >> 3;
  const int colT = (low3 + 8 * bbit) * 4 + cpos;
  const int col = colT * 16 + la;
  unsigned* fl1 = flags + rt * 128;       // stage1 (rhbf ready) epochs [64]
  unsigned* fl2 = flags + rt * 128 + 64;  // stage2 (h ready) epochs [64]

  for (int i = tid; i < 256; i += 128)
    h32loc[i] = h32g[(rt * 16 + (i >> 4)) * 1024 + colT * 16 + (i & 15)];

  // weights to VGPRs: wave0 Wz slice; wave1 Wr slice + full-K Wg slice
  const u16* w1p = (wave ? Wr : Wz) + (size_t)col * 1024 + kg * 8;
  bf16x8 wzr[32], wg[32];
#pragma unroll
  for (int ks = 0; ks < 32; ++ks) wzr[ks] = ld8(w1p + ks * 32);
  if (wave == 1) {
    const u16* wgp = Wg + (size_t)col * 1024 + kg * 8;
#pragma unroll
    for (int ks = 0; ks < 32; ++ks) wg[ks] = ld8(wgp + ks * 32);
  }

  // A(0) prologue prefetch into parity 0 (wave0)
  {
    int li = lane & 31;
    size_t off = (size_t)(rt * 16 + (li >> 1)) * 1024 + colT * 16 + (li & 1) * 8;
    if (wave == 0) {
      gload_lds16((lane < 32 ? Az : Ar) + off, &Abuf[0][0]);
      gload_lds16(Ag + off, &Abuf[0][512]);
    }
  }
  __syncthreads();

  const u16* hsrc = hbf + rt * 16 * 1024;
  const u16* rsrc = rhbf + rt * 16 * 1024;
  const int rowb = rt * 16 + kg * 4;

  for (int t = 0; t < S; ++t) {
    const int p = t & 1;
    // ---- stage 1: z (wave0) and r (wave1) ----
    poll64(fl2, (unsigned)t, lane);
    __builtin_amdgcn_fence(__ATOMIC_ACQUIRE, "agent");  // inv L1/L2; weights in VGPR
#pragma unroll
    for (int i = 0; i < 16; ++i)
      gload_lds16(hsrc + i * 1024 + wave * 512 + (lane ^ (i & 7)) * 8,
                  LDSh + i * 1024 + wave * 512 + lane * 8);
    __syncthreads();  // B1: h staged (+ wave0's A(t) DMA from last step drained)
    f32x4 p0 = {0.f, 0.f, 0.f, 0.f}, p1 = {0.f, 0.f, 0.f, 0.f};
#pragma unroll
    for (int ks = 0; ks < 32; ks += 2) {
      p0 = mfma16(ld8(LDSh + la * 1024 + (((ks * 4 + kg) ^ sw) << 3)), wzr[ks], p0);
      p1 = mfma16(ld8(LDSh + la * 1024 + ((((ks + 1) * 4 + kg) ^ sw) << 3)), wzr[ks + 1], p1);
    }
    if (wave == 0) {
#pragma unroll
      for (int e = 0; e < 4; ++e) {
        float av = b2f(Abuf[p][(kg * 4 + e) * 16 + la]);
        zloc[(kg * 4 + e) * 16 + la] = 1.f / (1.f + __expf(-(p0[e] + p1[e] + av)));
      }
    } else {
#pragma unroll
      for (int e = 0; e < 4; ++e) {
        float av = b2f(Abuf[p][256 + (kg * 4 + e) * 16 + la]);
        float rv = 1.f / (1.f + __expf(-(p0[e] + p1[e] + av)));
        st16(&rhbf[(rowb + e) * 1024 + col], f2b(rv * h32loc[(kg * 4 + e) * 16 + la]));
      }
      __builtin_amdgcn_s_waitcnt(0);  // only own rh stores outstanding -> fast
      if (lane == 0)
        __hip_atomic_store(&fl1[colT], (unsigned)(t + 1), __ATOMIC_RELAXED,
                           __HIP_MEMORY_SCOPE_AGENT);
    }
    // ---- stage 2: g (wave1 full-K) + h update; wave0 prefetches A(t+1) ----
    poll64(fl1, (unsigned)(t + 1), lane);
    __builtin_amdgcn_fence(__ATOMIC_ACQUIRE, "agent");
#pragma unroll
    for (int i = 0; i < 16; ++i)
      gload_lds16(rsrc + i * 1024 + wave * 512 + (lane ^ (i & 7)) * 8,
                  LDSh + i * 1024 + wave * 512 + lane * 8);
    __syncthreads();  // B2: rh staged; zloc visible to wave1
    if (wave == 0) {
      // A(t+1) prefetch; next barrier (B1 of t+1) is a full exchange away
      int tn = (t + 1 < S) ? (t + 1) : t;
      int li = lane & 31;
      size_t off = (size_t)tn * 32768 +
                   (size_t)(rt * 16 + (li >> 1)) * 1024 + colT * 16 + (li & 1) * 8;
      gload_lds16((lane < 32 ? Az : Ar) + off, &Abuf[p ^ 1][0]);
      gload_lds16(Ag + off, &Abuf[p ^ 1][512]);
    } else {
      f32x4 q0 = {0.f, 0.f, 0.f, 0.f}, q1 = {0.f, 0.f, 0.f, 0.f};
#pragma unroll
      for (int ks = 0; ks < 32; ks += 2) {
        q0 = mfma16(ld8(LDSh + la * 1024 + (((ks * 4 + kg) ^ sw) << 3)), wg[ks], q0);
        q1 = mfma16(ld8(LDSh + la * 1024 + ((((ks + 1) * 4 + kg) ^ sw) << 3)), wg[ks + 1], q1);
      }
      float hnv[4];
      u16 hbv[4];
#pragma unroll
      for (int e = 0; e < 4; ++e) {
        int li2 = (kg * 4 + e) * 16 + la;
        float av = b2f(Abuf[p][512 + (kg * 4 + e) * 16 + la]);
        float gs = q0[e] + q1[e] + av;
        float ex = __expf(2.f * gs);
        float g = 1.f - 2.f / (ex + 1.f);  // tanh, inf-safe
        float z = zloc[li2];
        float hn = (1.f - z) * h32loc[li2] + z * g;
        h32loc[li2] = hn;
        hnv[e] = hn;
        hbv[e] = f2b(hn);
        st16(&hbf[(rowb + e) * 1024 + col], hbv[e]);  // critical-path publish
      }
      __builtin_amdgcn_s_waitcnt(0);  // only own hbf stores outstanding
      if (lane == 0)
        __hip_atomic_store(&fl2[colT], (unsigned)(t + 1), __ATOMIC_RELAXED,
                           __HIP_MEMORY_SCOPE_AGENT);
      // off-critical-path: history + final-state snapshot (plain cached)
#pragma unroll
      for (int e = 0; e < 4; ++e) {
        hist[(size_t)((rowb + e) * S + t) * 1024 + col] = hbv[e];
        if (t == S - 1) h32g[(rowb + e) * 1024 + col] = hnv[e];
      }
    }
  }
}

// ---------------- host ----------------

extern "C" void kernel_launch(void* const* d_in, const int* in_sizes, int n_in,
                              void* d_out, int out_size, void* d_ws, size_t ws_size,
                              hipStream_t stream) {
  (void)in_sizes; (void)n_in; (void)out_size;
  const float* x   = (const float*)d_in[0];
  const float* h0  = (const float*)d_in[1];
  const float* Wzx = (const float*)d_in[2];
  const float* bz  = (const float*)d_in[3];
  const float* Wzh = (const float*)d_in[4];
  const float* Wrx = (const float*)d_in[5];
  const float* br  = (const float*)d_in[6];
  const float* Wrh = (const float*)d_in[7];
  const float* Wgx = (const float*)d_in[8];
  const float* bg  = (const float*)d_in[9];
  const float* Wgh = (const float*)d_in[10];
  const float* Wo  = (const float*)d_in[11];
  const float* bo  = (const float*)d_in[12];
  float* out = (float*)d_out;
  char* ws = (char*)d_ws;

  const size_t MB = 1024 * 1024;
  size_t o = 4096;  // flags live in [0,4096)
  u16* wWzx = (u16*)(ws + o); o += 4 * MB;   // [L=2][1024][1024] bf16
  u16* wWzh = (u16*)(ws + o); o += 4 * MB;
  u16* wWrx = (u16*)(ws + o); o += 4 * MB;
  u16* wWrh = (u16*)(ws + o); o += 4 * MB;
  u16* wWgx = (u16*)(ws + o); o += 4 * MB;
  u16* wWgh = (u16*)(ws + o); o += 4 * MB;
  u16* wWo  = (u16*)(ws + o); o += 2 * MB;
  u16* Az    = (u16*)(ws + o); o += 32 * MB;  // [512][32][1024] bf16 step-major
  u16* Ar    = (u16*)(ws + o); o += 32 * MB;
  u16* Ag    = (u16*)(ws + o); o += 32 * MB;
  u16* hist0 = (u16*)(ws + o); o += 32 * MB;  // [b*S+t][1024]
  u16* xbf   = (u16*)(ws + o); o += 32 * MB;  // x bf16; later reused as hist1
  float* h32_0 = (float*)(ws + o); o += 131072;
  float* h32_1 = (float*)(ws + o); o += 131072;
  u16* hbf_0 = (u16*)(ws + o); o += 65536;
  u16* hbf_1 = (u16*)(ws + o); o += 65536;
  u16* rhbf  = (u16*)(ws + o); o += 65536;

  if (ws_size < o) {
    fprintf(stderr, "[gru] INSUFFICIENT WORKSPACE ws=%zu need=%zu\n", ws_size, o);
    return;
  }
  unsigned* flags0 = (unsigned*)(ws + 0);
  unsigned* flags1 = (unsigned*)(ws + 2048);
  hipMemsetAsync(ws, 0, 4096, stream);

  // casts
  castk<<<dim3(8192), dim3(256), 0, stream>>>(Wzx, wWzx, 2097152);
  castk<<<dim3(8192), dim3(256), 0, stream>>>(Wzh, wWzh, 2097152);
  castk<<<dim3(8192), dim3(256), 0, stream>>>(Wrx, wWrx, 2097152);
  castk<<<dim3(8192), dim3(256), 0, stream>>>(Wrh, wWrh, 2097152);
  castk<<<dim3(8192), dim3(256), 0, stream>>>(Wgx, wWgx, 2097152);
  castk<<<dim3(8192), dim3(256), 0, stream>>>(Wgh, wWgh, 2097152);
  castk<<<dim3(4096), dim3(256), 0, stream>>>(Wo, wWo, 1048576);
  castk<<<dim3(65536), dim3(256), 0, stream>>>(x, xbf, 16777216);
  init_h<<<dim3(128), dim3(256), 0, stream>>>(h0, h32_0, h32_1, hbf_0, hbf_1);

  // layer0 input projections (step-major output)
  gemm_nt<2><<<dim3(1024), dim3(256), 0, stream>>>(xbf, wWzx, bz, Az, 16384, 1024, 1024);
  gemm_nt<2><<<dim3(1024), dim3(256), 0, stream>>>(xbf, wWrx, br, Ar, 16384, 1024, 1024);
  gemm_nt<2><<<dim3(1024), dim3(256), 0, stream>>>(xbf, wWgx, bg, Ag, 16384, 1024, 1024);

  // layer0 recurrence
  gru_layer5<<<dim3(128), dim3(128), 0, stream>>>(wWzh, wWrh, wWgh, Az, Ar, Ag, hist0,
                                                  h32_0, hbf_0, rhbf, flags0, 512);

  // layer1 input projections (from h0 history)
  gemm_nt<2><<<dim3(1024), dim3(256), 0, stream>>>(hist0, wWzx + 1048576, bz + 1024, Az, 16384, 1024, 1024);
  gemm_nt<2><<<dim3(1024), dim3(256), 0, stream>>>(hist0, wWrx + 1048576, br + 1024, Ar, 16384, 1024, 1024);
  gemm_nt<2><<<dim3(1024), dim3(256), 0, stream>>>(hist0, wWgx + 1048576, bg + 1024, Ag, 16384, 1024, 1024);

  // layer1 recurrence (hist1 lives in xbf region - x no longer needed)
  gru_layer5<<<dim3(128), dim3(128), 0, stream>>>(wWzh + 1048576, wWrh + 1048576,
                                                  wWgh + 1048576, Az, Ar, Ag, xbf,
                                                  h32_1, hbf_1, rhbf, flags1, 512);

  // output projection
  gemm_nt<0><<<dim3(1024), dim3(256), 0, stream>>>(xbf, wWo, bo, out, 16384, 1024, 1024);

  // final hidden states
  final_h<<<dim3(128), dim3(256), 0, stream>>>(h32_0, h32_1, out + 16777216);
}